// Round 4
// baseline (768.524 us; speedup 1.0000x reference)
//
#include <hip/hip_runtime.h>

typedef __bf16 bf16x8 __attribute__((ext_vector_type(8)));
typedef __bf16 bf16x4 __attribute__((ext_vector_type(4)));
typedef float  f32x4  __attribute__((ext_vector_type(4)));

#define MFMA(A,B,C) __builtin_amdgcn_mfma_f32_16x16x32_bf16((A),(B),(C),0,0,0)
// wave-local LDS RAW/WAR fence; sched_barrier stops reordering past the wait (rule #18)
#define LDS_FENCE() do { asm volatile("s_waitcnt lgkmcnt(0)" ::: "memory"); \
                         __builtin_amdgcn_sched_barrier(0); } while (0)

// ---------------- geometry ----------------
// vid: (4, 256, 256, 256) fp32. windows: 4*32*32 = 4096, each 64 tokens x 256 ch.
// NH=8, hd=32, scale = 32^-0.5.
//
// Round-4 structure: 512-thread blocks, 8 waves, ONE HEAD PER WAVE.
//   - per-wave gemms are N=32 (own head's q/k/v cols), kt-outer, A re-read from LDS
//   - frags held across barrier: aq[4]+bk[4]+bv[2][2] = 80 VGPR; S processed in
//     two mt-halves (32 VGPR) -> peak ~120 regs -> 4 waves/SIMD (16 waves/CU)
//   - LDS 49152 B -> 2 blocks/CU: XO 32768 (x -> attn-out, XOR-swizzled) +
//     8 x 2048 per-wave tile scratch
//   - phase barriers: stage | gemms | attention | proj  (x dead before attn-out)

constexpr int OFF_XO = 0;        // 64 rows * 512 B, swizzled
constexpr int OFF_SC = 32768;    // 8 waves * 2048 B (16x64 bf16 tile each)
constexpr int LDS_BYTES = 49152; // 2 * 49152 = 98304 <= 163840

// XOR-swizzle: row-major bf16, stride 256 (XO) / 64 (scratch); ^((row&7)<<4)
// makes the 16-lane column-slice b128 reads hit 8 distinct 4-bank slots
// (throughput-optimal) while keeping 16B alignment.
__device__ __forceinline__ int xo_addr(int row, int col) {
    return (row * 512 + col * 2) ^ ((row & 7) << 4);
}
__device__ __forceinline__ int sc_addr(int row, int col) {
    return (row * 128 + col * 2) ^ ((row & 7) << 4);
}

// ---------------- weight re-pack: B-fragment order ----------------
// wfrag[ct][kt][lane][j], ct 0..47 = concat(q,k,v) col-tiles, ct 48..63 = proj.
__global__ void prep_weights(const float* __restrict__ wq,
                             const float* __restrict__ wkv,
                             const float* __restrict__ projw,
                             __bf16* __restrict__ wfrag)
{
    const int lane = threadIdx.x & 63;
    const int kt   = threadIdx.x >> 6;       // 0..7
    const int ct   = blockIdx.x;             // 0..63
    const int nl   = lane & 15;
    const int kk0  = kt * 32 + ((lane >> 4) << 3);
    __bf16* dst = wfrag + (((size_t)ct * 8 + kt) * 64 + lane) * 8;
    bf16x8 o;
#pragma unroll
    for (int j = 0; j < 8; ++j) {
        const int kk = kk0 + j;
        float v;
        if (ct < 16)       v = wq  [kk * 256 +             ct        * 16 + nl];
        else if (ct < 32)  v = wkv [kk * 512 +             (ct - 16) * 16 + nl];
        else if (ct < 48)  v = wkv [kk * 512 + 256 +       (ct - 32) * 16 + nl];
        else               v = projw[kk * 256 +            (ct - 48) * 16 + nl];
        o[j] = (__bf16)v;
    }
    *(bf16x8*)dst = o;
}

// ---------------- rel-pos bias -> C-layout f32x4 fragments ----------------
// biasf[((h*4+mt)*4+nt)*64 + lane] = {bias[q(mt,lane,r)][k(nt,lane)] : r=0..3}
__global__ void prep_bias(const float* __restrict__ table, float* __restrict__ biasf)
{
    const int g    = blockIdx.x * 256 + threadIdx.x;   // 0..8191
    const int lane = g & 63;
    const int nt   = (g >> 6) & 3;
    const int mt   = (g >> 8) & 3;
    const int h    = g >> 10;
    const int colL = lane & 15;
    const int rowC = (lane >> 4) << 2;
    const int k     = nt * 16 + colL;
    const int kcode = (k >> 3) * 15 + (k & 7);
    f32x4 o;
#pragma unroll
    for (int r = 0; r < 4; ++r) {
        const int q     = mt * 16 + rowC + r;
        const int qcode = (q >> 3) * 15 + (q & 7) + 112;   // (dy+7)*15 + (dx+7)
        o[r] = table[(qcode - kcode) * 8 + h];
    }
    ((f32x4*)biasf)[g] = o;
}

// ---------------- fused per-window kernel ----------------
__global__ __launch_bounds__(512, 4)   // 4 waves/EU target -> cap 128 regs/wave
void attn_fused(const float* __restrict__ vid,
                const float* __restrict__ mod,
                const float* __restrict__ bq,
                const float* __restrict__ bkv,
                const float* __restrict__ projb,
                const float* __restrict__ biasf,
                const __bf16* __restrict__ wfrag,
                float* __restrict__ out)
{
    extern __shared__ char smem[];
    char* xo = smem + OFF_XO;                              // x -> attn-out
    char* sc = smem + OFF_SC + (threadIdx.x >> 6) * 2048;  // per-wave 16x64 tile

    const int tid  = threadIdx.x;
    const int lane = tid & 63;
    const int wv   = tid >> 6;          // wave 0..7 == head
    const int colL = lane & 15;
    const int quad = lane >> 4;
    const int kq   = quad << 3;         // A/B frag k-offset
    const int rowC = quad << 2;         // C/D row base
    const int h    = wv;

    const int b  = blockIdx.x;
    const int tt = b >> 10;
    const int wy = (b >> 5) & 31;
    const int wx = b & 31;
    const int base0 = tt * (1 << 24) + wy * 8 * 65536 + wx * 8 * 256;

    // ---- stage x + modulator (fp32 add, bf16 store, swizzled) ----
#pragma unroll
    for (int i = 0; i < 8; ++i) {
        const int idx = tid + 512 * i;        // 0..4095
        const int m  = idx >> 6;              // wave-uniform row
        const int c4 = (idx & 63) << 2;
        const int py = m >> 3, px = m & 7;
        const float4 xv = *(const float4*)(vid + base0 + py * 65536 + px * 256 + c4);
        const float4 mv = *(const float4*)(mod + m * 256 + c4);
        bf16x4 o;
        o[0] = (__bf16)(xv.x + mv.x);
        o[1] = (__bf16)(xv.y + mv.y);
        o[2] = (__bf16)(xv.z + mv.z);
        o[3] = (__bf16)(xv.w + mv.w);
        *(bf16x4*)(xo + xo_addr(m, c4)) = o;
    }
    __syncthreads();

    // ---- per-head N=32 gemm: [64x256] @ [256x32], kt-outer, A re-read ----
    auto gemm2 = [&](int ct0, const float* __restrict__ bias_p, f32x4 (&acc)[2][4]) {
        const float b0 = bias_p[colL], b1 = bias_p[16 + colL];
#pragma unroll
        for (int mt = 0; mt < 4; ++mt) {
            acc[0][mt] = {b0, b0, b0, b0};
            acc[1][mt] = {b1, b1, b1, b1};
        }
#pragma unroll
        for (int kt = 0; kt < 8; ++kt) {
            bf16x8 a[4];
#pragma unroll
            for (int mt = 0; mt < 4; ++mt)
                a[mt] = *(const bf16x8*)(xo + xo_addr(mt * 16 + colL, kt * 32 + kq));
#pragma unroll
            for (int n = 0; n < 2; ++n) {
                const bf16x8 bf =
                    *((const bf16x8*)wfrag + ((size_t)(ct0 + n) * 8 + kt) * 64 + lane);
#pragma unroll
                for (int mt = 0; mt < 4; ++mt)
                    acc[n][mt] = MFMA(a[mt], bf, acc[n][mt]);
            }
        }
    };

    const float SCALE = 0.17677669529663687f;   // 32^-0.5
    bf16x8 aq[4], bk[4], bv[2][2];

    // v first (smallest held frag set afterwards): v^T tiles [16ch x 64tok]
    {
        f32x4 acc[2][4];
        gemm2(32 + 2 * h, bkv + 256 + h * 32, acc);
#pragma unroll
        for (int n = 0; n < 2; ++n) {
#pragma unroll
            for (int mt = 0; mt < 4; ++mt) {
                bf16x4 o;
                o[0] = (__bf16)acc[n][mt][0]; o[1] = (__bf16)acc[n][mt][1];
                o[2] = (__bf16)acc[n][mt][2]; o[3] = (__bf16)acc[n][mt][3];
                *(bf16x4*)(sc + sc_addr(colL, mt * 16 + rowC)) = o;
            }
            LDS_FENCE();
#pragma unroll
            for (int k2 = 0; k2 < 2; ++k2)
                bv[n][k2] = *(const bf16x8*)(sc + sc_addr(colL, k2 * 32 + kq));
            LDS_FENCE();
        }
    }

    // q: tile-PAIRS staged side by side (cols t*32) -> aq[4]
    {
        f32x4 acc[2][4];
        gemm2(2 * h, bq + h * 32, acc);
#pragma unroll
        for (int g = 0; g < 2; ++g) {
#pragma unroll
            for (int t = 0; t < 2; ++t)
#pragma unroll
                for (int n = 0; n < 2; ++n)
#pragma unroll
                    for (int r = 0; r < 4; ++r)
                        *(__bf16*)(sc + sc_addr(rowC + r, t * 32 + n * 16 + colL)) =
                            (__bf16)(acc[n][2 * g + t][r] * SCALE);
            LDS_FENCE();
#pragma unroll
            for (int t = 0; t < 2; ++t)
                aq[2 * g + t] = *(const bf16x8*)(sc + sc_addr(colL, t * 32 + kq));
            LDS_FENCE();
        }
    }

    // k: same -> bk[4]
    {
        f32x4 acc[2][4];
        gemm2(16 + 2 * h, bkv + h * 32, acc);
#pragma unroll
        for (int g = 0; g < 2; ++g) {
#pragma unroll
            for (int t = 0; t < 2; ++t)
#pragma unroll
                for (int n = 0; n < 2; ++n)
#pragma unroll
                    for (int r = 0; r < 4; ++r)
                        *(__bf16*)(sc + sc_addr(rowC + r, t * 32 + n * 16 + colL)) =
                            (__bf16)acc[n][2 * g + t][r];
            LDS_FENCE();
#pragma unroll
            for (int t = 0; t < 2; ++t)
                bk[2 * g + t] = *(const bf16x8*)(sc + sc_addr(colL, t * 32 + kq));
            LDS_FENCE();
        }
    }
    __syncthreads();   // ALL waves done reading x; XO becomes attn-out

    // ---- attention (one head), S in two mt-halves to bound registers ----
    const f32x4* __restrict__ bfr = (const f32x4*)biasf;
#pragma unroll
    for (int H = 0; H < 2; ++H) {
        f32x4 S[2][4];
#pragma unroll
        for (int m = 0; m < 2; ++m)
#pragma unroll
            for (int nt = 0; nt < 4; ++nt)
                S[m][nt] = MFMA(aq[2 * H + m], bk[nt],
                                bfr[((h * 4 + 2 * H + m) * 4 + nt) * 64 + lane]);

        // softmax over 64 k-cols (4 nt in-lane x 16 colL lanes)
#pragma unroll
        for (int m = 0; m < 2; ++m)
#pragma unroll
            for (int r = 0; r < 4; ++r) {
                float mx = S[m][0][r];
#pragma unroll
                for (int nt = 1; nt < 4; ++nt) mx = fmaxf(mx, S[m][nt][r]);
                mx = fmaxf(mx, __shfl_xor(mx, 1));
                mx = fmaxf(mx, __shfl_xor(mx, 2));
                mx = fmaxf(mx, __shfl_xor(mx, 4));
                mx = fmaxf(mx, __shfl_xor(mx, 8));
                float sum = 0.f;
#pragma unroll
                for (int nt = 0; nt < 4; ++nt) {
                    const float e = __expf(S[m][nt][r] - mx);
                    S[m][nt][r] = e;
                    sum += e;
                }
                sum += __shfl_xor(sum, 1);
                sum += __shfl_xor(sum, 2);
                sum += __shfl_xor(sum, 4);
                sum += __shfl_xor(sum, 8);
                const float inv = 1.0f / sum;
#pragma unroll
                for (int nt = 0; nt < 4; ++nt) S[m][nt][r] *= inv;
            }

        // P tile-transpose + PV; attn-out -> XO (swizzled)
#pragma unroll
        for (int m = 0; m < 2; ++m) {
#pragma unroll
            for (int nt = 0; nt < 4; ++nt)
#pragma unroll
                for (int r = 0; r < 4; ++r)
                    *(__bf16*)(sc + sc_addr(rowC + r, nt * 16 + colL)) = (__bf16)S[m][nt][r];
            LDS_FENCE();
            const bf16x8 ap0 = *(const bf16x8*)(sc + sc_addr(colL, kq));
            const bf16x8 ap1 = *(const bf16x8*)(sc + sc_addr(colL, 32 + kq));
            LDS_FENCE();
#pragma unroll
            for (int n2 = 0; n2 < 2; ++n2) {
                f32x4 o = {0.f, 0.f, 0.f, 0.f};
                o = MFMA(ap0, bv[n2][0], o);
                o = MFMA(ap1, bv[n2][1], o);
#pragma unroll
                for (int r = 0; r < 4; ++r)
                    *(__bf16*)(xo + xo_addr((2 * H + m) * 16 + rowC + r,
                                            h * 32 + n2 * 16 + colL)) = (__bf16)o[r];
            }
        }
    }
    __syncthreads();

    // ---- proj: [64x256] @ [256x32] per wave + scatter back to vid layout ----
    {
        f32x4 acc[2][4];
        gemm2(48 + 2 * wv, projb + wv * 32, acc);
#pragma unroll
        for (int n = 0; n < 2; ++n) {
            const int nn = wv * 32 + n * 16 + colL;
#pragma unroll
            for (int mt = 0; mt < 4; ++mt)
#pragma unroll
                for (int r = 0; r < 4; ++r) {
                    const int m = mt * 16 + rowC + r;
                    out[base0 + (m >> 3) * 65536 + (m & 7) * 256 + nn] = acc[n][mt][r];
                }
        }
    }
}

extern "C" void kernel_launch(void* const* d_in, const int* in_sizes, int n_in,
                              void* d_out, int out_size, void* d_ws, size_t ws_size,
                              hipStream_t stream)
{
    const float* vid  = (const float*)d_in[0];
    const float* mod  = (const float*)d_in[1];
    const float* wq   = (const float*)d_in[2];
    const float* bq   = (const float*)d_in[3];
    const float* wkv  = (const float*)d_in[4];
    const float* bkv  = (const float*)d_in[5];
    const float* pw   = (const float*)d_in[6];
    const float* pb   = (const float*)d_in[7];
    const float* tab  = (const float*)d_in[8];
    __bf16* wfrag = (__bf16*)d_ws;                         // 512 KB
    float*  biasf = (float*)((char*)d_ws + 524288);        // 128 KB

    prep_weights<<<64, 512, 0, stream>>>(wq, wkv, pw, wfrag);
    prep_bias<<<32, 256, 0, stream>>>(tab, biasf);

    (void)hipFuncSetAttribute((const void*)attn_fused,
                              hipFuncAttributeMaxDynamicSharedMemorySize, LDS_BYTES);
    attn_fused<<<4096, 512, LDS_BYTES, stream>>>(vid, mod, bq, bkv, pb, biasf, wfrag,
                                                 (float*)d_out);
}